// Round 1
// 1273.612 us; speedup vs baseline: 1.1020x; 1.1020x over previous
//
#include <hip/hip_runtime.h>

typedef __attribute__((ext_vector_type(8))) short bf16x8;
typedef __attribute__((ext_vector_type(4))) float f32x4;

#define MFMA_BF16(a,b,c) __builtin_amdgcn_mfma_f32_16x16x32_bf16(a,b,c,0,0,0)

#define H_ 16
#define DH 64
#define LQ 2112      // 2048 S-queries + 64 NS
#define LK 4160      // 4096 S-keys + 64 NS
#define QOFF 2048    // q_pos = QOFF + q_row
#define DM 1024
#define NO 3072

__device__ __forceinline__ unsigned short f2bf(float f) {
  union { float f; unsigned u; } v; v.f = f;
  unsigned u = v.u;
  return (unsigned short)((u + 0x7FFFu + ((u >> 16) & 1u)) >> 16);
}

// async global->LDS, 16B per lane, wave-uniform LDS base + lane*16
__device__ __forceinline__ void gl_lds16(const unsigned short* g, unsigned short* l) {
  __builtin_amdgcn_global_load_lds(
      (const __attribute__((address_space(1))) unsigned int*)g,
      (__attribute__((address_space(3))) unsigned int*)l,
      16, 0, 0);
}

// ---------------- fp32 -> bf16 convert of x ----------------
__global__ __launch_bounds__(256) void cvt_x(const float* __restrict__ x,
                                             unsigned short* __restrict__ xb) {
  int i = blockIdx.x * 256 + threadIdx.x;   // 4160*1024/4 elements of float4
  float4 f = ((const float4*)x)[i];
  ushort4 o;
  o.x = f2bf(f.x); o.y = f2bf(f.y); o.z = f2bf(f.z); o.w = f2bf(f.w);
  ((ushort4*)xb)[i] = o;
}

// ---------------- transpose fp32 (R x C) -> bf16 (C x R) ----------------
__global__ __launch_bounds__(256) void transp_bf(const float* __restrict__ in,
                                                 unsigned short* __restrict__ out,
                                                 int R, int C) {
  __shared__ float t[32][33];
  int c0 = blockIdx.x * 32, r0 = blockIdx.y * 32;
  #pragma unroll
  for (int i = threadIdx.y; i < 32; i += 8)
    t[i][threadIdx.x] = in[(size_t)(r0 + i) * C + c0 + threadIdx.x];
  __syncthreads();
  #pragma unroll
  for (int i = threadIdx.y; i < 32; i += 8)
    out[(size_t)(c0 + i) * R + r0 + threadIdx.x] = f2bf(t[threadIdx.x][i]);
}

// ---------------- qkv_NS: per-position GEMV, fp32, atomic d-split ----------------
// grid (3 oc, 4 dc, 64 n), block 256
__global__ __launch_bounds__(256) void qkv_ns_k(const float* __restrict__ x,
                                                const float* __restrict__ W_NS,
                                                float* __restrict__ qkvNS) {
  int oc = blockIdx.x, dc = blockIdx.y, n = blockIdx.z;
  __shared__ float xs[256];
  xs[threadIdx.x] = x[(size_t)(4096 + n) * DM + dc * 256 + threadIdx.x];
  __syncthreads();
  int o0 = oc * 1024 + threadIdx.x * 4;
  const float* W = W_NS + ((size_t)n * DM + dc * 256) * NO + o0;
  float a0 = 0.f, a1 = 0.f, a2 = 0.f, a3 = 0.f;
  #pragma unroll 4
  for (int d = 0; d < 256; ++d) {
    float xv = xs[d];
    float4 w = *(const float4*)(W + (size_t)d * NO);
    a0 = fmaf(xv, w.x, a0); a1 = fmaf(xv, w.y, a1);
    a2 = fmaf(xv, w.z, a2); a3 = fmaf(xv, w.w, a3);
  }
  float* dst = qkvNS + (size_t)n * NO + o0;
  atomicAdd(dst + 0, a0); atomicAdd(dst + 1, a1);
  atomicAdd(dst + 2, a2); atomicAdd(dst + 3, a3);
}

// ---------------- scatter qkv_NS into head-major Q/K bf16 + transposed V ----------------
__global__ __launch_bounds__(256) void scatter_ns(const float* __restrict__ qkvNS,
                                                  unsigned short* __restrict__ Qb,
                                                  unsigned short* __restrict__ Kb,
                                                  unsigned short* __restrict__ VbT) {
  int i = blockIdx.x * 256 + threadIdx.x;  // 64*3072
  int n = i / NO, o = i - n * NO;
  float v = qkvNS[i];
  int h = (o & 1023) >> 6, dh = o & 63;
  if (o < 1024)       Qb[((size_t)h * LQ + 2048 + n) * DH + dh] = f2bf(v * 0.125f);
  else if (o < 2048)  Kb[((size_t)h * LK + 4096 + n) * DH + dh] = f2bf(v);
  else                VbT[((size_t)(h * 64 + dh)) * LK + 4096 + n] = f2bf(v);
}

// ---------------- 128x128 bf16 MFMA GEMM: qkv_S (global_load_lds staging) ----------------
// A = xb (4096 x 1024), BT = WST (3072 x 1024). grid (32, 24), block 256.
__global__ __launch_bounds__(256) void gemm_qkv(const unsigned short* __restrict__ A,
                                                const unsigned short* __restrict__ BT,
                                                unsigned short* __restrict__ Qb,
                                                unsigned short* __restrict__ Kb,
                                                unsigned short* __restrict__ VbT) {
  __shared__ unsigned short At[128 * 32];
  __shared__ unsigned short Bt[128 * 32];
  int tm = blockIdx.x * 128, tn = blockIdx.y * 128;
  int tid = threadIdx.x, wave = tid >> 6, lane = tid & 63;
  int col = lane & 15, quad = lane >> 4;
  int wr = (wave & 1) * 64, wc = (wave >> 1) * 64;
  int srow = tid >> 2, spart = (tid & 3) * 8;

  f32x4 acc[4][4] = {};

  for (int kb = 0; kb < DM; kb += 32) {
    __syncthreads();
    gl_lds16(&A[(size_t)(tm + srow) * DM + kb + spart],       &At[wave * 512]);
    gl_lds16(&A[(size_t)(tm + srow + 64) * DM + kb + spart],  &At[2048 + wave * 512]);
    gl_lds16(&BT[(size_t)(tn + srow) * DM + kb + spart],      &Bt[wave * 512]);
    gl_lds16(&BT[(size_t)(tn + srow + 64) * DM + kb + spart], &Bt[2048 + wave * 512]);
    __syncthreads();
    bf16x8 af[4], bfr[4];
    #pragma unroll
    for (int i = 0; i < 4; ++i) {
      af[i]  = *(const bf16x8*)&At[(wr + i * 16 + col) * 32 + quad * 8];
      bfr[i] = *(const bf16x8*)&Bt[(wc + i * 16 + col) * 32 + quad * 8];
    }
    #pragma unroll
    for (int i = 0; i < 4; ++i)
      #pragma unroll
      for (int j = 0; j < 4; ++j)
        acc[i][j] = MFMA_BF16(af[i], bfr[j], acc[i][j]);
  }

  if (tn >= 2048) {
    // V output, written TRANSPOSED: VbT[h][dh][k-pos], 4 rows pack into one ushort4
    #pragma unroll
    for (int i = 0; i < 4; ++i)
      #pragma unroll
      for (int j = 0; j < 4; ++j) {
        int n = tn + wc + j * 16 + col;
        int h = (n & 1023) >> 6, dh = n & 63;
        int m0 = tm + wr + i * 16 + quad * 4;
        ushort4 o;
        o.x = f2bf(acc[i][j][0]); o.y = f2bf(acc[i][j][1]);
        o.z = f2bf(acc[i][j][2]); o.w = f2bf(acc[i][j][3]);
        *(ushort4*)&VbT[((size_t)(h * 64 + dh)) * LK + m0] = o;
      }
  } else if (tn >= 1024) {
    #pragma unroll
    for (int i = 0; i < 4; ++i)
      #pragma unroll
      for (int j = 0; j < 4; ++j)
        #pragma unroll
        for (int r = 0; r < 4; ++r) {
          int m = tm + wr + i * 16 + quad * 4 + r;
          int n = tn + wc + j * 16 + col;
          int h = (n & 1023) >> 6, dh = n & 63;
          Kb[((size_t)h * LK + m) * DH + dh] = f2bf(acc[i][j][r]);
        }
  } else {
    #pragma unroll
    for (int i = 0; i < 4; ++i)
      #pragma unroll
      for (int j = 0; j < 4; ++j)
        #pragma unroll
        for (int r = 0; r < 4; ++r) {
          int m = tm + wr + i * 16 + quad * 4 + r;
          int n = tn + wc + j * 16 + col;
          int h = (n & 1023) >> 6, dh = n & 63;
          if (m >= QOFF) Qb[((size_t)h * LQ + (m - QOFF)) * DH + dh] = f2bf(acc[i][j][r] * 0.125f);
        }
  }
}

// ---------------- flash attention, KVBLK=64, double-buffered, 1 barrier/tile ----------------
// grid (33 q-tiles, 16 heads), block 256 (4 waves x 16 q-rows)
__global__ __launch_bounds__(256) void attn(const unsigned short* __restrict__ Qb,
                                            const unsigned short* __restrict__ Kb,
                                            const unsigned short* __restrict__ VbT,
                                            unsigned short* __restrict__ Ob) {
  __shared__ unsigned short Kt[2][64 * 64];   // [k_local][d], chunk-swizzled by row&7
  __shared__ unsigned short Vt[2][64 * 64];   // [d][k_local], chunk-swizzled by row&7
  __shared__ unsigned short Pt[4][16 * 72];   // per-wave P [q_local][k_local], pad 72
  int h = blockIdx.y;
  int qb = blockIdx.x * 64;
  int tid = threadIdx.x, wave = tid >> 6, lane = tid & 63;
  int col = lane & 15, quad = lane >> 4;
  const unsigned short* Qh = Qb + (size_t)h * LQ * DH;
  const unsigned short* Kh = Kb + (size_t)h * LK * DH;
  const unsigned short* Vh = VbT + (size_t)h * 64 * LK;   // [64 d][LK]

  int qrow = qb + wave * 16 + col;           // A-frag m index = lane&15
  bf16x8 aq0 = *(const bf16x8*)&Qh[qrow * DH + quad * 8];
  bf16x8 aq1 = *(const bf16x8*)&Qh[qrow * DH + 32 + quad * 8];

  f32x4 oacc[4] = {};
  float m_i[4] = {-3e38f, -3e38f, -3e38f, -3e38f};
  float l_i[4] = {0.f, 0.f, 0.f, 0.f};

  int row0 = tid >> 3;                          // 0..31 (LDS row of first chunk)
  int sc8  = ((tid & 7) ^ (row0 & 7)) * 8;      // pre-swizzled global chunk offset
  int xs   = col & 7;                           // read-side swizzle (row&7 == col&7)

#define STAGE(b, kb_) do { \
    gl_lds16(&Kh[(size_t)((kb_) + row0) * DH + sc8],        &Kt[b][wave * 512]); \
    gl_lds16(&Kh[(size_t)((kb_) + row0 + 32) * DH + sc8],   &Kt[b][2048 + wave * 512]); \
    gl_lds16(&Vh[(size_t)row0 * LK + (kb_) + sc8],          &Vt[b][wave * 512]); \
    gl_lds16(&Vh[(size_t)(row0 + 32) * LK + (kb_) + sc8],   &Vt[b][2048 + wave * 512]); \
  } while (0)

  int nkt = 33 + blockIdx.x;
  STAGE(0, 0);
  int cur = 0;
  for (int kt = 0; kt < nkt; ++kt) {
    int kb = kt << 6;
    __syncthreads();                       // drains this tile's loads; frees other buffer
    if (kt + 1 < nkt) STAGE(cur ^ 1, (kt + 1) << 6);   // prefetch overlaps compute below

    const unsigned short* K_ = Kt[cur];
    const unsigned short* V_ = Vt[cur];

    f32x4 s[4] = {};
    #pragma unroll
    for (int f = 0; f < 4; ++f) {
      int krow = (f * 16 + col) * 64;
      bf16x8 b0 = *(const bf16x8*)&K_[krow + (quad ^ xs) * 8];
      bf16x8 b1 = *(const bf16x8*)&K_[krow + (((4 + quad) ^ xs)) * 8];
      s[f] = MFMA_BF16(aq0, b0, s[f]);
      s[f] = MFMA_BF16(aq1, b1, s[f]);
    }

    float alpha[4];
    bool lastt = (kt == nkt - 1);
    #pragma unroll
    for (int r = 0; r < 4; ++r) {
      float v0 = s[0][r], v1 = s[1][r], v2 = s[2][r], v3 = s[3][r];
      if (lastt) {
        int kmax = QOFF + qb + wave * 16 + quad * 4 + r;  // inclusive causal bound
        v0 = (kb + col      <= kmax) ? v0 : -3e38f;
        v1 = (kb + 16 + col <= kmax) ? v1 : -3e38f;
        v2 = (kb + 32 + col <= kmax) ? v2 : -3e38f;
        v3 = (kb + 48 + col <= kmax) ? v3 : -3e38f;
      }
      float t = fmaxf(fmaxf(v0, v1), fmaxf(v2, v3));
      t = fmaxf(t, __shfl_xor(t, 1));
      t = fmaxf(t, __shfl_xor(t, 2));
      t = fmaxf(t, __shfl_xor(t, 4));
      t = fmaxf(t, __shfl_xor(t, 8));
      float mn = fmaxf(m_i[r], t);
      alpha[r] = __expf(m_i[r] - mn);
      m_i[r] = mn;
      float e0 = __expf(v0 - mn), e1 = __expf(v1 - mn);
      float e2 = __expf(v2 - mn), e3 = __expf(v3 - mn);
      float su = (e0 + e1) + (e2 + e3);
      su += __shfl_xor(su, 1);
      su += __shfl_xor(su, 2);
      su += __shfl_xor(su, 4);
      su += __shfl_xor(su, 8);
      l_i[r] = l_i[r] * alpha[r] + su;
      int pr = (quad * 4 + r) * 72;
      Pt[wave][pr + col]      = f2bf(e0);
      Pt[wave][pr + 16 + col] = f2bf(e1);
      Pt[wave][pr + 32 + col] = f2bf(e2);
      Pt[wave][pr + 48 + col] = f2bf(e3);
    }
    #pragma unroll
    for (int dt = 0; dt < 4; ++dt)
      #pragma unroll
      for (int r = 0; r < 4; ++r) oacc[dt][r] *= alpha[r];

    asm volatile("s_waitcnt lgkmcnt(0)" ::: "memory");  // cross-lane P visibility (same wave)
    bf16x8 ap0 = *(const bf16x8*)&Pt[wave][col * 72 + quad * 8];
    bf16x8 ap1 = *(const bf16x8*)&Pt[wave][col * 72 + 32 + quad * 8];
    #pragma unroll
    for (int dt = 0; dt < 4; ++dt) {
      int dr = (dt * 16 + col) * 64;
      bf16x8 bv0 = *(const bf16x8*)&V_[dr + (quad ^ xs) * 8];
      bf16x8 bv1 = *(const bf16x8*)&V_[dr + (((4 + quad) ^ xs)) * 8];
      oacc[dt] = MFMA_BF16(ap0, bv0, oacc[dt]);
      oacc[dt] = MFMA_BF16(ap1, bv1, oacc[dt]);
    }
    cur ^= 1;
  }
#undef STAGE

  #pragma unroll
  for (int r = 0; r < 4; ++r) {
    int q = qb + wave * 16 + quad * 4 + r;
    float inv = 1.0f / l_i[r];
    #pragma unroll
    for (int dt = 0; dt < 4; ++dt)
      Ob[(size_t)q * DM + h * DH + dt * 16 + col] = f2bf(oacc[dt][r] * inv);
  }
}

// ---------------- out-projection GEMM: (2112x1024) @ (1024x1024) -> fp32 ----------------
// grid (17, 8)
__global__ __launch_bounds__(256) void gemm_out_k(const unsigned short* __restrict__ A,
                                                  const unsigned short* __restrict__ BT,
                                                  float* __restrict__ C) {
  __shared__ unsigned short At[128 * 32];
  __shared__ unsigned short Bt[128 * 32];
  int tm = blockIdx.x * 128, tn = blockIdx.y * 128;
  int tid = threadIdx.x, wave = tid >> 6, lane = tid & 63;
  int col = lane & 15, quad = lane >> 4;
  int wr = (wave & 1) * 64, wc = (wave >> 1) * 64;
  int srow = tid >> 2, spart = (tid & 3) * 8;
  int ar0 = min(tm + srow, LQ - 1);
  int ar1 = min(tm + srow + 64, LQ - 1);

  f32x4 acc[4][4] = {};

  for (int kb = 0; kb < DM; kb += 32) {
    __syncthreads();
    gl_lds16(&A[(size_t)ar0 * DM + kb + spart],               &At[wave * 512]);
    gl_lds16(&A[(size_t)ar1 * DM + kb + spart],               &At[2048 + wave * 512]);
    gl_lds16(&BT[(size_t)(tn + srow) * DM + kb + spart],      &Bt[wave * 512]);
    gl_lds16(&BT[(size_t)(tn + srow + 64) * DM + kb + spart], &Bt[2048 + wave * 512]);
    __syncthreads();
    bf16x8 af[4], bfr[4];
    #pragma unroll
    for (int i = 0; i < 4; ++i) {
      af[i]  = *(const bf16x8*)&At[(wr + i * 16 + col) * 32 + quad * 8];
      bfr[i] = *(const bf16x8*)&Bt[(wc + i * 16 + col) * 32 + quad * 8];
    }
    #pragma unroll
    for (int i = 0; i < 4; ++i)
      #pragma unroll
      for (int j = 0; j < 4; ++j)
        acc[i][j] = MFMA_BF16(af[i], bfr[j], acc[i][j]);
  }

  #pragma unroll
  for (int i = 0; i < 4; ++i)
    #pragma unroll
    for (int j = 0; j < 4; ++j)
      #pragma unroll
      for (int r = 0; r < 4; ++r) {
        int m = tm + wr + i * 16 + quad * 4 + r;
        int n = tn + wc + j * 16 + col;
        if (m < LQ) C[(size_t)m * DM + n] = acc[i][j][r];
      }
}

extern "C" void kernel_launch(void* const* d_in, const int* in_sizes, int n_in,
                              void* d_out, int out_size, void* d_ws, size_t ws_size,
                              hipStream_t stream) {
  const float* x     = (const float*)d_in[0];
  const float* W_S   = (const float*)d_in[1];
  const float* W_NS  = (const float*)d_in[2];
  const float* W_out = (const float*)d_in[3];
  char* ws = (char*)d_ws;

  unsigned short* xb    = (unsigned short*)(ws + 0);          // 4160*1024 bf16
  unsigned short* WST   = (unsigned short*)(ws + 8519680);    // 3072*1024 bf16 (W_S^T)
  unsigned short* WOT   = (unsigned short*)(ws + 14811136);   // 1024*1024 bf16 (W_out^T)
  float*          qkvNS = (float*)(ws + 16908288);            // 64*3072 fp32
  unsigned short* Qb    = (unsigned short*)(ws + 17694720);   // 16*2112*64 bf16 (pre-scaled)
  unsigned short* Kb    = (unsigned short*)(ws + 22020096);   // 16*4160*64 bf16
  unsigned short* VbT   = (unsigned short*)(ws + 30539776);   // 16*64*4160 bf16 (V transposed)
  unsigned short* Ob    = (unsigned short*)(ws + 39059456);   // 2112*1024 bf16
  float* out = (float*)d_out;

  hipMemsetAsync(qkvNS, 0, 64 * NO * sizeof(float), stream);
  cvt_x<<<4160, 256, 0, stream>>>(x, xb);
  transp_bf<<<dim3(96, 32), dim3(32, 8), 0, stream>>>(W_S, WST, 1024, 3072);
  transp_bf<<<dim3(32, 32), dim3(32, 8), 0, stream>>>(W_out, WOT, 1024, 1024);
  qkv_ns_k<<<dim3(3, 4, 64), 256, 0, stream>>>(x, W_NS, qkvNS);
  scatter_ns<<<768, 256, 0, stream>>>(qkvNS, Qb, Kb, VbT);
  gemm_qkv<<<dim3(32, 24), 256, 0, stream>>>(xb, WST, Qb, Kb, VbT);
  attn<<<dim3(33, 16), 256, 0, stream>>>(Qb, Kb, VbT, Ob);
  gemm_out_k<<<dim3(17, 8), 256, 0, stream>>>(Ob, WOT, out);
}

// Round 2
// 1263.354 us; speedup vs baseline: 1.1110x; 1.0081x over previous
//
#include <hip/hip_runtime.h>

typedef __attribute__((ext_vector_type(8))) short bf16x8;
typedef __attribute__((ext_vector_type(4))) float f32x4;

#define MFMA_BF16(a,b,c) __builtin_amdgcn_mfma_f32_16x16x32_bf16(a,b,c,0,0,0)

#define H_ 16
#define DH 64
#define LQ 2112      // 2048 S-queries + 64 NS
#define LK 4160      // 4096 S-keys + 64 NS
#define QOFF 2048    // q_pos = QOFF + q_row
#define DM 1024
#define NO 3072
#define QSCALE 0.1803368801f   // 0.125 * log2(e): softmax done in exp2 domain

__device__ __forceinline__ unsigned short f2bf(float f) {
  union { float f; unsigned u; } v; v.f = f;
  unsigned u = v.u;
  return (unsigned short)((u + 0x7FFFu + ((u >> 16) & 1u)) >> 16);
}

// async global->LDS, 16B per lane, wave-uniform LDS base + lane*16
__device__ __forceinline__ void gl_lds16(const unsigned short* g, unsigned short* l) {
  __builtin_amdgcn_global_load_lds(
      (const __attribute__((address_space(1))) unsigned int*)g,
      (__attribute__((address_space(3))) unsigned int*)l,
      16, 0, 0);
}

// ---------------- prep: cvt_x + transp(W_S) + transp(W_out), one launch ----------------
// grid 8256: [0,4160) cvt_x, [4160,7232) W_S transpose, [7232,8256) W_out transpose
__global__ __launch_bounds__(256) void prep(const float* __restrict__ x,
                                            const float* __restrict__ W_S,
                                            const float* __restrict__ W_out,
                                            unsigned short* __restrict__ xb,
                                            unsigned short* __restrict__ WST,
                                            unsigned short* __restrict__ WOT) {
  int idx = blockIdx.x, tid = threadIdx.x;
  if (idx < 4160) {
    int i = idx * 256 + tid;
    float4 f = ((const float4*)x)[i];
    ushort4 o;
    o.x = f2bf(f.x); o.y = f2bf(f.y); o.z = f2bf(f.z); o.w = f2bf(f.w);
    ((ushort4*)xb)[i] = o;
    return;
  }
  __shared__ float t[32][33];
  const float* in; unsigned short* out; int C, bx, by;
  if (idx < 7232) { int r = idx - 4160; bx = r % 96; by = r / 96; in = W_S;   out = WST; C = 3072; }
  else            { int r = idx - 7232; bx = r % 32; by = r / 32; in = W_out; out = WOT; C = 1024; }
  int c0 = bx * 32, r0 = by * 32;
  int tx = tid & 31, ty = tid >> 5;
  #pragma unroll
  for (int i = ty; i < 32; i += 8)
    t[i][tx] = in[(size_t)(r0 + i) * C + c0 + tx];
  __syncthreads();
  #pragma unroll
  for (int i = ty; i < 32; i += 8)
    out[(size_t)(c0 + i) * 1024 + r0 + tx] = f2bf(t[tx][i]);
}

// ---------------- fused qkv: S-GEMM (MFMA) + NS-GEMV (HBM-bound) in one launch ----------
// grid 1152. idx%3==2 -> NS role (384 blocks); else GEMM role (768 blocks, 32x24 tiles).
// Roles interleave so BW-bound NS blocks and MFMA-bound GEMM blocks co-reside per CU.
__global__ __launch_bounds__(256) void fused_qkv(const unsigned short* __restrict__ A,
                                                 const unsigned short* __restrict__ BT,
                                                 const float* __restrict__ x,
                                                 const float* __restrict__ W_NS,
                                                 unsigned short* __restrict__ Qb,
                                                 unsigned short* __restrict__ Kb,
                                                 unsigned short* __restrict__ VbT) {
  int idx = blockIdx.x, tid = threadIdx.x;

  if (idx % 3 == 2) {
    // ---- NS role: per-position GEMV, full d=1024 per block, no atomics ----
    __shared__ float xs[1024];
    int nid = idx / 3;            // 0..383
    int oc2 = nid % 6, n = nid / 6;
    ((float4*)xs)[tid] = ((const float4*)(x + (size_t)(4096 + n) * DM))[tid];
    __syncthreads();
    int o0 = oc2 * 512 + tid * 2;
    const float* W = W_NS + (size_t)n * DM * NO + o0;
    float a0 = 0.f, a1 = 0.f;
    #pragma unroll 8
    for (int d = 0; d < DM; ++d) {
      float xv = xs[d];
      float2 w = *(const float2*)(W + (size_t)d * NO);
      a0 = fmaf(xv, w.x, a0); a1 = fmaf(xv, w.y, a1);
    }
    #pragma unroll
    for (int j = 0; j < 2; ++j) {
      int o = o0 + j;
      float v = j ? a1 : a0;
      int h = (o & 1023) >> 6, dh = o & 63;
      if (o < 1024)       Qb[((size_t)h * LQ + 2048 + n) * DH + dh] = f2bf(v * QSCALE);
      else if (o < 2048)  Kb[((size_t)h * LK + 4096 + n) * DH + dh] = f2bf(v);
      else                VbT[((size_t)(h * 64 + dh)) * LK + 4096 + n] = f2bf(v);
    }
    return;
  }

  // ---- GEMM role: 128x128 bf16 MFMA, global_load_lds staging ----
  __shared__ unsigned short At[128 * 32];
  __shared__ unsigned short Bt[128 * 32];
  int g = (idx / 3) * 2 + (idx % 3);       // 0..767
  int tm = (g & 31) * 128, tn = (g >> 5) * 128;
  int wave = tid >> 6, lane = tid & 63;
  int col = lane & 15, quad = lane >> 4;
  int wr = (wave & 1) * 64, wc = (wave >> 1) * 64;
  int srow = tid >> 2, spart = (tid & 3) * 8;

  f32x4 acc[4][4] = {};

  for (int kb = 0; kb < DM; kb += 32) {
    __syncthreads();
    gl_lds16(&A[(size_t)(tm + srow) * DM + kb + spart],       &At[wave * 512]);
    gl_lds16(&A[(size_t)(tm + srow + 64) * DM + kb + spart],  &At[2048 + wave * 512]);
    gl_lds16(&BT[(size_t)(tn + srow) * DM + kb + spart],      &Bt[wave * 512]);
    gl_lds16(&BT[(size_t)(tn + srow + 64) * DM + kb + spart], &Bt[2048 + wave * 512]);
    __syncthreads();
    bf16x8 af[4], bfr[4];
    #pragma unroll
    for (int i = 0; i < 4; ++i) {
      af[i]  = *(const bf16x8*)&At[(wr + i * 16 + col) * 32 + quad * 8];
      bfr[i] = *(const bf16x8*)&Bt[(wc + i * 16 + col) * 32 + quad * 8];
    }
    #pragma unroll
    for (int i = 0; i < 4; ++i)
      #pragma unroll
      for (int j = 0; j < 4; ++j)
        acc[i][j] = MFMA_BF16(af[i], bfr[j], acc[i][j]);
  }

  if (tn >= 2048) {
    // V output, written TRANSPOSED: VbT[h][dh][k-pos], 4 rows pack into one ushort4
    #pragma unroll
    for (int i = 0; i < 4; ++i)
      #pragma unroll
      for (int j = 0; j < 4; ++j) {
        int n = tn + wc + j * 16 + col;
        int h = (n & 1023) >> 6, dh = n & 63;
        int m0 = tm + wr + i * 16 + quad * 4;
        ushort4 o;
        o.x = f2bf(acc[i][j][0]); o.y = f2bf(acc[i][j][1]);
        o.z = f2bf(acc[i][j][2]); o.w = f2bf(acc[i][j][3]);
        *(ushort4*)&VbT[((size_t)(h * 64 + dh)) * LK + m0] = o;
      }
  } else if (tn >= 1024) {
    #pragma unroll
    for (int i = 0; i < 4; ++i)
      #pragma unroll
      for (int j = 0; j < 4; ++j)
        #pragma unroll
        for (int r = 0; r < 4; ++r) {
          int m = tm + wr + i * 16 + quad * 4 + r;
          int n = tn + wc + j * 16 + col;
          int h = (n & 1023) >> 6, dh = n & 63;
          Kb[((size_t)h * LK + m) * DH + dh] = f2bf(acc[i][j][r]);
        }
  } else {
    #pragma unroll
    for (int i = 0; i < 4; ++i)
      #pragma unroll
      for (int j = 0; j < 4; ++j)
        #pragma unroll
        for (int r = 0; r < 4; ++r) {
          int m = tm + wr + i * 16 + quad * 4 + r;
          int n = tn + wc + j * 16 + col;
          int h = (n & 1023) >> 6, dh = n & 63;
          if (m >= QOFF) Qb[((size_t)h * LQ + (m - QOFF)) * DH + dh] = f2bf(acc[i][j][r] * QSCALE);
        }
  }
}

// ---------------- flash attention, KVBLK=64, double-buffered, 1 barrier/tile ----------------
// grid (33 q-tiles, 16 heads), block 256 (4 waves x 16 q-rows). exp2 softmax domain.
__global__ __launch_bounds__(256) void attn(const unsigned short* __restrict__ Qb,
                                            const unsigned short* __restrict__ Kb,
                                            const unsigned short* __restrict__ VbT,
                                            unsigned short* __restrict__ Ob) {
  __shared__ unsigned short Kt[2][64 * 64];   // [k_local][d], chunk-swizzled by row&7
  __shared__ unsigned short Vt[2][64 * 64];   // [d][k_local], chunk-swizzled by row&7
  __shared__ unsigned short Pt[4][16 * 72];   // per-wave P [q_local][k_local], pad 72
  int h = blockIdx.y;
  int qi = 32 - (int)blockIdx.x;             // LPT: longest blocks dispatch first
  int qb = qi * 64;
  int tid = threadIdx.x, wave = tid >> 6, lane = tid & 63;
  int col = lane & 15, quad = lane >> 4;
  const unsigned short* Qh = Qb + (size_t)h * LQ * DH;
  const unsigned short* Kh = Kb + (size_t)h * LK * DH;
  const unsigned short* Vh = VbT + (size_t)h * 64 * LK;   // [64 d][LK]

  int qrow = qb + wave * 16 + col;           // A-frag m index = lane&15
  bf16x8 aq0 = *(const bf16x8*)&Qh[qrow * DH + quad * 8];
  bf16x8 aq1 = *(const bf16x8*)&Qh[qrow * DH + 32 + quad * 8];

  f32x4 oacc[4] = {};
  float m_i[4] = {-3e38f, -3e38f, -3e38f, -3e38f};
  float l_i[4] = {0.f, 0.f, 0.f, 0.f};

  int row0 = tid >> 3;                          // 0..31 (LDS row of first chunk)
  int sc8  = ((tid & 7) ^ (row0 & 7)) * 8;      // pre-swizzled global chunk offset
  int xs   = col & 7;                           // read-side swizzle (row&7 == col&7)

#define STAGE(b, kb_) do { \
    gl_lds16(&Kh[(size_t)((kb_) + row0) * DH + sc8],        &Kt[b][wave * 512]); \
    gl_lds16(&Kh[(size_t)((kb_) + row0 + 32) * DH + sc8],   &Kt[b][2048 + wave * 512]); \
    gl_lds16(&Vh[(size_t)row0 * LK + (kb_) + sc8],          &Vt[b][wave * 512]); \
    gl_lds16(&Vh[(size_t)(row0 + 32) * LK + (kb_) + sc8],   &Vt[b][2048 + wave * 512]); \
  } while (0)

  int nkt = 33 + qi;
  STAGE(0, 0);
  int cur = 0;
  for (int kt = 0; kt < nkt; ++kt) {
    int kb = kt << 6;
    __syncthreads();                       // drains this tile's loads; frees other buffer
    if (kt + 1 < nkt) STAGE(cur ^ 1, (kt + 1) << 6);   // prefetch overlaps compute below

    const unsigned short* K_ = Kt[cur];
    const unsigned short* V_ = Vt[cur];

    f32x4 s[4] = {};
    __builtin_amdgcn_s_setprio(1);
    #pragma unroll
    for (int f = 0; f < 4; ++f) {
      int krow = (f * 16 + col) * 64;
      bf16x8 b0 = *(const bf16x8*)&K_[krow + (quad ^ xs) * 8];
      bf16x8 b1 = *(const bf16x8*)&K_[krow + (((4 + quad) ^ xs)) * 8];
      s[f] = MFMA_BF16(aq0, b0, s[f]);
      s[f] = MFMA_BF16(aq1, b1, s[f]);
    }
    __builtin_amdgcn_s_setprio(0);

    float alpha[4];
    bool lastt = (kt == nkt - 1);
    #pragma unroll
    for (int r = 0; r < 4; ++r) {
      float v0 = s[0][r], v1 = s[1][r], v2 = s[2][r], v3 = s[3][r];
      if (lastt) {
        int kmax = QOFF + qb + wave * 16 + quad * 4 + r;  // inclusive causal bound
        v0 = (kb + col      <= kmax) ? v0 : -3e38f;
        v1 = (kb + 16 + col <= kmax) ? v1 : -3e38f;
        v2 = (kb + 32 + col <= kmax) ? v2 : -3e38f;
        v3 = (kb + 48 + col <= kmax) ? v3 : -3e38f;
      }
      float t = fmaxf(fmaxf(v0, v1), fmaxf(v2, v3));
      t = fmaxf(t, __shfl_xor(t, 1));
      t = fmaxf(t, __shfl_xor(t, 2));
      t = fmaxf(t, __shfl_xor(t, 4));
      t = fmaxf(t, __shfl_xor(t, 8));
      float mn = fmaxf(m_i[r], t);
      alpha[r] = exp2f(m_i[r] - mn);       // scores already in log2 domain (QSCALE)
      m_i[r] = mn;
      float e0 = exp2f(v0 - mn), e1 = exp2f(v1 - mn);
      float e2 = exp2f(v2 - mn), e3 = exp2f(v3 - mn);
      float su = (e0 + e1) + (e2 + e3);
      su += __shfl_xor(su, 1);
      su += __shfl_xor(su, 2);
      su += __shfl_xor(su, 4);
      su += __shfl_xor(su, 8);
      l_i[r] = l_i[r] * alpha[r] + su;
      int pr = (quad * 4 + r) * 72;
      Pt[wave][pr + col]      = f2bf(e0);
      Pt[wave][pr + 16 + col] = f2bf(e1);
      Pt[wave][pr + 32 + col] = f2bf(e2);
      Pt[wave][pr + 48 + col] = f2bf(e3);
    }
    #pragma unroll
    for (int dt = 0; dt < 4; ++dt)
      #pragma unroll
      for (int r = 0; r < 4; ++r) oacc[dt][r] *= alpha[r];

    asm volatile("s_waitcnt lgkmcnt(0)" ::: "memory");  // cross-lane P visibility (same wave)
    bf16x8 ap0 = *(const bf16x8*)&Pt[wave][col * 72 + quad * 8];
    bf16x8 ap1 = *(const bf16x8*)&Pt[wave][col * 72 + 32 + quad * 8];
    __builtin_amdgcn_s_setprio(1);
    #pragma unroll
    for (int dt = 0; dt < 4; ++dt) {
      int dr = (dt * 16 + col) * 64;
      bf16x8 bv0 = *(const bf16x8*)&V_[dr + (quad ^ xs) * 8];
      bf16x8 bv1 = *(const bf16x8*)&V_[dr + (((4 + quad) ^ xs)) * 8];
      oacc[dt] = MFMA_BF16(ap0, bv0, oacc[dt]);
      oacc[dt] = MFMA_BF16(ap1, bv1, oacc[dt]);
    }
    __builtin_amdgcn_s_setprio(0);
    cur ^= 1;
  }
#undef STAGE

  #pragma unroll
  for (int r = 0; r < 4; ++r) {
    int q = qb + wave * 16 + quad * 4 + r;
    float inv = 1.0f / l_i[r];
    #pragma unroll
    for (int dt = 0; dt < 4; ++dt)
      Ob[(size_t)q * DM + h * DH + dt * 16 + col] = f2bf(oacc[dt][r] * inv);
  }
}

// ---------------- out-projection GEMM: (2112x1024) @ (1024x1024) -> fp32 ----------------
// grid (17, 8)
__global__ __launch_bounds__(256) void gemm_out_k(const unsigned short* __restrict__ A,
                                                  const unsigned short* __restrict__ BT,
                                                  float* __restrict__ C) {
  __shared__ unsigned short At[128 * 32];
  __shared__ unsigned short Bt[128 * 32];
  int tm = blockIdx.x * 128, tn = blockIdx.y * 128;
  int tid = threadIdx.x, wave = tid >> 6, lane = tid & 63;
  int col = lane & 15, quad = lane >> 4;
  int wr = (wave & 1) * 64, wc = (wave >> 1) * 64;
  int srow = tid >> 2, spart = (tid & 3) * 8;
  int ar0 = min(tm + srow, LQ - 1);
  int ar1 = min(tm + srow + 64, LQ - 1);

  f32x4 acc[4][4] = {};

  for (int kb = 0; kb < DM; kb += 32) {
    __syncthreads();
    gl_lds16(&A[(size_t)ar0 * DM + kb + spart],               &At[wave * 512]);
    gl_lds16(&A[(size_t)ar1 * DM + kb + spart],               &At[2048 + wave * 512]);
    gl_lds16(&BT[(size_t)(tn + srow) * DM + kb + spart],      &Bt[wave * 512]);
    gl_lds16(&BT[(size_t)(tn + srow + 64) * DM + kb + spart], &Bt[2048 + wave * 512]);
    __syncthreads();
    bf16x8 af[4], bfr[4];
    #pragma unroll
    for (int i = 0; i < 4; ++i) {
      af[i]  = *(const bf16x8*)&At[(wr + i * 16 + col) * 32 + quad * 8];
      bfr[i] = *(const bf16x8*)&Bt[(wc + i * 16 + col) * 32 + quad * 8];
    }
    #pragma unroll
    for (int i = 0; i < 4; ++i)
      #pragma unroll
      for (int j = 0; j < 4; ++j)
        acc[i][j] = MFMA_BF16(af[i], bfr[j], acc[i][j]);
  }

  #pragma unroll
  for (int i = 0; i < 4; ++i)
    #pragma unroll
    for (int j = 0; j < 4; ++j)
      #pragma unroll
      for (int r = 0; r < 4; ++r) {
        int m = tm + wr + i * 16 + quad * 4 + r;
        int n = tn + wc + j * 16 + col;
        if (m < LQ) C[(size_t)m * DM + n] = acc[i][j][r];
      }
}

extern "C" void kernel_launch(void* const* d_in, const int* in_sizes, int n_in,
                              void* d_out, int out_size, void* d_ws, size_t ws_size,
                              hipStream_t stream) {
  const float* x     = (const float*)d_in[0];
  const float* W_S   = (const float*)d_in[1];
  const float* W_NS  = (const float*)d_in[2];
  const float* W_out = (const float*)d_in[3];
  char* ws = (char*)d_ws;

  unsigned short* xb    = (unsigned short*)(ws + 0);          // 4160*1024 bf16
  unsigned short* WST   = (unsigned short*)(ws + 8519680);    // 3072*1024 bf16 (W_S^T)
  unsigned short* WOT   = (unsigned short*)(ws + 14811136);   // 1024*1024 bf16 (W_out^T)
  unsigned short* Qb    = (unsigned short*)(ws + 17694720);   // 16*2112*64 bf16 (pre-scaled)
  unsigned short* Kb    = (unsigned short*)(ws + 22020096);   // 16*4160*64 bf16
  unsigned short* VbT   = (unsigned short*)(ws + 30539776);   // 16*64*4160 bf16 (V transposed)
  unsigned short* Ob    = (unsigned short*)(ws + 39059456);   // 2112*1024 bf16
  float* out = (float*)d_out;

  prep<<<8256, 256, 0, stream>>>(x, W_S, W_out, xb, WST, WOT);
  fused_qkv<<<1152, 256, 0, stream>>>(xb, WST, x, W_NS, Qb, Kb, VbT);
  attn<<<dim3(33, 16), 256, 0, stream>>>(Qb, Kb, VbT, Ob);
  gemm_out_k<<<dim3(17, 8), 256, 0, stream>>>(Ob, WOT, out);
}